// Round 9
// baseline (480.377 us; speedup 1.0000x reference)
//
#include <hip/hip_runtime.h>
#include <stdint.h>

#define T_LEN 512
#define IN0   9
#define H     56
#define BG    8
#define NW    14
#define NTH   (NW * 64)        // 896 threads, 14 waves; wave w owns n' in [16w,16w+16)
#define NBLK  256

typedef __attribute__((ext_vector_type(8))) short bfrag;   // 8 bf16
typedef __attribute__((ext_vector_type(4))) float ffrag;   // 4 fp32

#define MFMA(a,b,c) __builtin_amdgcn_mfma_f32_16x16x32_bf16((a),(b),(c),0,0,0)

__device__ __forceinline__ uint32_t bf16hi(float x) {
  uint32_t u = __float_as_uint(x);
  return (u + 0x7FFFu + ((u >> 16) & 1u)) & 0xFFFF0000u;
}
__device__ __forceinline__ void split_bf16(float x, short& hs, short& ls) {
  uint32_t hb = bf16hi(x);
  float lf = x - __uint_as_float(hb);
  hs = (short)(hb >> 16);
  ls = (short)(bf16hi(lf) >> 16);
}
__device__ __forceinline__ float rcp_f(float v)  { return __builtin_amdgcn_rcpf(v); }
__device__ __forceinline__ float sigm_f(float v) { return rcp_f(1.0f + __expf(-v)); }
__device__ __forceinline__ float tanh_f(float v) { return 1.0f - 2.0f * rcp_f(1.0f + __expf(2.0f * v)); }

__global__ __launch_bounds__(NTH, 4)
void lstm_mfma5(const float* __restrict__ x,
                const float* __restrict__ w_ih0, const float* __restrict__ w_hh0,
                const float* __restrict__ b_ih0, const float* __restrict__ b_hh0,
                const float* __restrict__ w_ih1, const float* __restrict__ w_hh1,
                const float* __restrict__ b_ih1, const float* __restrict__ b_hh1,
                const float* __restrict__ fc1_w, const float* __restrict__ fc1_b,
                const float* __restrict__ fc2_w, const float* __restrict__ fc2_b,
                float* __restrict__ out)
{
  // h-state as MFMA B-operand: B[k = h-element j (L0: k56..63 = x)][n = batch-slot]
  // cols n 0..7 = hi(h for batch n), cols 8..15 = lo residual. Fragment-linear.
  // sB[0],sB[1] = layer0 input (h0 + x) parity buffers; sB[2],sB[3] = h1.
  __shared__ __align__(16) short sB[4][1024];
  __shared__ float sF[BG * H];
  __shared__ float sY[BG * 28];

  const int tid  = threadIdx.x;
  const int lane = tid & 63;
  const int w    = tid >> 6;
  const int c16  = lane & 15;
  const int quad = lane >> 4;

  const int np   = 16 * w + c16;       // n' = 4j+g (A-operand M index)
  const int jb   = np >> 2, gb = np & 3;
  const int wrow = gb * H + jb;

  for (int i = tid; i < (int)(sizeof(sB) / 4); i += NTH) ((int*)sB)[i] = 0;

  // ---- A-fragments (weights, bf16 hi/lo): A[m=c16][k=quad*8+jj] ----
  bfrag B0h[2], B0l[2], Buh[2], Bul[2], Bhh[2], Bhl[2];
  #pragma unroll
  for (int s = 0; s < 2; ++s) {
    union { short sh[8]; bfrag v; } a0h, a0l, auh, aul, ahh, ahl;
    #pragma unroll
    for (int jj = 0; jj < 8; ++jj) {
      const int k = 32 * s + quad * 8 + jj;
      const float w0 = (k < H) ? w_hh0[wrow * H + k] : w_ih0[wrow * IN0 + (k - 56)];
      const float wu = (k < H) ? w_ih1[wrow * H + k] : 0.0f;
      const float wh = (k < H) ? w_hh1[wrow * H + k] : 0.0f;
      split_bf16(w0, a0h.sh[jj], a0l.sh[jj]);
      split_bf16(wu, auh.sh[jj], aul.sh[jj]);
      split_bf16(wh, ahh.sh[jj], ahl.sh[jj]);
    }
    B0h[s] = a0h.v; B0l[s] = a0l.v;
    Buh[s] = auh.v; Bul[s] = aul.v;
    Bhh[s] = ahh.v; Bhl[s] = ahl.v;
  }

  // D rows m = 4*quad + r -> gate g=r of j4 = 4w+quad. Bias rides C on hi cols only.
  const int j4 = 4 * w + quad;
  ffrag bias0f, bias1f;
  #pragma unroll
  for (int r = 0; r < 4; ++r) {
    const float v0 = b_ih0[r * H + j4] + b_hh0[r * H + j4];
    const float v1 = b_ih1[r * H + j4] + b_hh1[r * H + j4];
    bias0f[r] = (c16 < 8) ? v0 : 0.0f;
    bias1f[r] = (c16 < 8) ? v1 : 0.0f;
  }

  // act identity: lay=0 (c16<8) -> act1 element (b, j4); lay=1 -> act0 (b, j4)
  const int lay = (lane >> 3) & 1;
  const int b   = lane & 7;
  float wx8a[4];
  #pragma unroll
  for (int r = 0; r < 4; ++r)
    wx8a[r] = lay ? w_ih0[(r * H + j4) * IN0 + 8] : 0.0f;

  // h store offsets: element (k=j4, n=b) hi, (k=j4, n=b+8) lo (+64 shorts)
  const int kk   = j4 & 31;
  const int offE = (j4 >> 5) * 512 + ((kk >> 3) * 16 + b) * 8 + (kk & 7);
  short* const hp0 = &sB[0][0] + (lay ? 0 : 3 * 1024) + offE;  // RR=0 regions
  short* const hp1 = &sB[0][0] + (lay ? 1 * 1024 : 2 * 1024) + offE;  // RR=1 + prologue

  // x staging identity (wave 0 only): lanes shalf==1 cover (sbq 0..7, sjlc 0..3)
  const int shalf = lane >> 5;
  const int sbq   = (lane >> 2) & 7;
  const int sjlc  = lane & 3;
  const int offX  = 512 + (48 + sbq) * 8 + 2 * sjlc;
  short* const xst0 = &sB[0][0] + offX;
  short* const xst1 = &sB[1][0] + offX;
  const short* const sBr = &sB[0][0];

  const float* xp8 = x + (size_t)(blockIdx.x * BG + b)   * T_LEN * IN0 + 8;
  const float* xps = x + (size_t)(blockIdx.x * BG + sbq) * T_LEN * IN0 + IN0 + 2 * sjlc;

  float cst = 0.f;                     // lay0: c1, lay1: c0
  __syncthreads();                     // sB zeros visible

  // ---- stage x(0) into sB[0] ----
  if (w == 0 && shalf) {
    const float xa = xps[-IN0], xb = xps[1 - IN0];
    short ah, al2, bh, bl2;
    split_bf16(xa, ah, al2); split_bf16(xb, bh, bl2);
    *(uint32_t*)xst0        = (uint16_t)ah  | ((uint32_t)(uint16_t)bh  << 16);
    *(uint32_t*)(xst0 + 64) = (uint16_t)al2 | ((uint32_t)(uint16_t)bl2 << 16);
  }
  __syncthreads();

  // ---- prologue: L0(0) gates + act0(0) -> h0(0) into sB[1]; stage x(1) ----
  {
    bfrag U0 = *(const bfrag*)(sBr + lane * 8);
    bfrag U1 = *(const bfrag*)(sBr + 512 + lane * 8);
    ffrag a0 = MFMA(B0h[0], U0, bias0f);
    a0 = MFMA(B0h[1], U1, a0);
    a0 = MFMA(B0l[0], U0, a0);
    a0 = MFMA(B0l[1], U1, a0);
    const float x8v = xp8[0];
    xp8 += IN0;
    float s0[4];
    #pragma unroll
    for (int r = 0; r < 4; ++r) s0[r] = a0[r] + __shfl_xor(a0[r], 8);
    if (lay) {
      const float gi = fmaf(wx8a[0], x8v, s0[0]);
      const float gf = fmaf(wx8a[1], x8v, s0[1]);
      const float gg = fmaf(wx8a[2], x8v, s0[2]);
      const float go = fmaf(wx8a[3], x8v, s0[3]);
      const float iv = sigm_f(gi), fv = sigm_f(gf), gv = tanh_f(gg), ov = sigm_f(go);
      cst = fmaf(fv, cst, iv * gv);
      const float hv = ov * tanh_f(cst);
      short hs, hl; split_bf16(hv, hs, hl);
      hp1[0] = hs; hp1[64] = hl;
    }
    if (w == 0 && shalf) {
      const float xa = xps[0], xb = xps[1];
      short ah, al2, bh, bl2;
      split_bf16(xa, ah, al2); split_bf16(xb, bh, bl2);
      *(uint32_t*)xst1        = (uint16_t)ah  | ((uint32_t)(uint16_t)bh  << 16);
      *(uint32_t*)(xst1 + 64) = (uint16_t)al2 | ((uint32_t)(uint16_t)bl2 << 16);
      xps += IN0;
    }
    __syncthreads();
  }

#define REGION(RR, L0PART, XSTG, LASTR)                                         \
  {                                                                             \
    bfrag U0 = *(const bfrag*)(sBr + (RR ^ 1) * 1024 + lane * 8);               \
    bfrag U1 = *(const bfrag*)(sBr + (RR ^ 1) * 1024 + 512 + lane * 8);         \
    bfrag H0 = *(const bfrag*)(sBr + (2 + RR) * 1024 + lane * 8);               \
    bfrag H1 = *(const bfrag*)(sBr + (2 + RR) * 1024 + 512 + lane * 8);         \
    float x8v = 0.0f;                                                           \
    if (L0PART) { x8v = xp8[0]; xp8 += IN0; }                                   \
    ffrag a1 = MFMA(Bhh[0], H0, bias1f);                                        \
    a1 = MFMA(Bhh[1], H1, a1);                                                  \
    a1 = MFMA(Bhl[0], H0, a1);                                                  \
    a1 = MFMA(Bhl[1], H1, a1);                                                  \
    a1 = MFMA(Buh[0], U0, a1);                                                  \
    a1 = MFMA(Buh[1], U1, a1);                                                  \
    a1 = MFMA(Bul[0], U0, a1);                                                  \
    a1 = MFMA(Bul[1], U1, a1);                                                  \
    ffrag a0 = a1;                                                              \
    if (L0PART) {                                                               \
      a0 = MFMA(B0h[0], U0, bias0f);                                            \
      a0 = MFMA(B0h[1], U1, a0);                                                \
      a0 = MFMA(B0l[0], U0, a0);                                                \
      a0 = MFMA(B0l[1], U1, a0);                                                \
    }                                                                           \
    if (!LASTR) {                                                               \
      float s1[4], s0[4];                                                       \
      _Pragma("unroll")                                                         \
      for (int r = 0; r < 4; ++r) s1[r] = a1[r] + __shfl_xor(a1[r], 8);         \
      _Pragma("unroll")                                                         \
      for (int r = 0; r < 4; ++r) s0[r] = a0[r] + __shfl_xor(a0[r], 8);         \
      const float g0s = lay ? s0[0] : s1[0];                                    \
      const float g1s = lay ? s0[1] : s1[1];                                    \
      const float g2s = lay ? s0[2] : s1[2];                                    \
      const float g3s = lay ? s0[3] : s1[3];                                    \
      const float gi = fmaf(wx8a[0], x8v, g0s);                                 \
      const float gf = fmaf(wx8a[1], x8v, g1s);                                 \
      const float gg = fmaf(wx8a[2], x8v, g2s);                                 \
      const float go = fmaf(wx8a[3], x8v, g3s);                                 \
      const float iv = sigm_f(gi), fv = sigm_f(gf);                             \
      const float gv = tanh_f(gg), ov = sigm_f(go);                             \
      cst = fmaf(fv, cst, iv * gv);                                             \
      const float hv = ov * tanh_f(cst);                                        \
      short hs, hl; split_bf16(hv, hs, hl);                                     \
      short* hb = (RR == 0) ? hp0 : hp1;                                        \
      hb[0] = hs; hb[64] = hl;                                                  \
    } else {                                                                    \
      float s1[4];                                                              \
      _Pragma("unroll")                                                         \
      for (int r = 0; r < 4; ++r) s1[r] = a1[r] + __shfl_xor(a1[r], 8);         \
      if (lay == 0) {                                                           \
        const float iv = sigm_f(s1[0]), fv = sigm_f(s1[1]);                     \
        const float gv = tanh_f(s1[2]), ov = sigm_f(s1[3]);                     \
        cst = fmaf(fv, cst, iv * gv);                                           \
        sF[b * H + j4] = ov * tanh_f(cst);                                      \
      }                                                                         \
    }                                                                           \
    if (XSTG) {                                                                 \
      if (w == 0 && shalf) {                                                    \
        const float xa = xps[0], xb = xps[1];                                   \
        short ah, al2, bh, bl2;                                                 \
        split_bf16(xa, ah, al2); split_bf16(xb, bh, bl2);                       \
        short* xb_ = (RR == 0) ? xst0 : xst1;                                   \
        *(uint32_t*)xb_        = (uint16_t)ah  | ((uint32_t)(uint16_t)bh  << 16); \
        *(uint32_t*)(xb_ + 64) = (uint16_t)al2 | ((uint32_t)(uint16_t)bl2 << 16); \
        xps += IN0;                                                             \
      }                                                                         \
    }                                                                           \
    __syncthreads();                                                            \
  }

  // t = 0..509 (255 pairs), then 510 (no staging), then 511 (L1-only)
  for (int it = 0; it < 255; ++it) {
    REGION(0, 1, 1, 0)
    REGION(1, 1, 1, 0)
  }
  REGION(0, 1, 0, 0)
  REGION(1, 0, 0, 1)
#undef REGION

  // ---- FC head on final h1 ----
  if (tid < 28 * BG) {
    const int m  = tid >> 3;
    const int bb = tid & 7;
    float acc = fc1_b[m];
    const float4* w4 = (const float4*)(fc1_w + m * H);
    const float4* h4 = (const float4*)(sF + bb * H);
    #pragma unroll
    for (int qq = 0; qq < H / 4; ++qq) {
      const float4 wv4 = w4[qq], hv4 = h4[qq];
      acc = fmaf(wv4.x, hv4.x, acc);
      acc = fmaf(wv4.y, hv4.y, acc);
      acc = fmaf(wv4.z, hv4.z, acc);
      acc = fmaf(wv4.w, hv4.w, acc);
    }
    sY[bb * 28 + m] = fmaxf(acc, 0.0f);
  }
  __syncthreads();
  if (tid < BG) {
    float acc = fc2_b[0];
    #pragma unroll
    for (int m = 0; m < 28; ++m)
      acc = fmaf(fc2_w[m], sY[tid * 28 + m], acc);
    out[blockIdx.x * BG + tid] = acc;
  }
}

extern "C" void kernel_launch(void* const* d_in, const int* in_sizes, int n_in,
                              void* d_out, int out_size, void* d_ws, size_t ws_size,
                              hipStream_t stream)
{
  const float* x     = (const float*)d_in[0];
  const float* w_ih0 = (const float*)d_in[1];
  const float* w_hh0 = (const float*)d_in[2];
  const float* b_ih0 = (const float*)d_in[3];
  const float* b_hh0 = (const float*)d_in[4];
  const float* w_ih1 = (const float*)d_in[5];
  const float* w_hh1 = (const float*)d_in[6];
  const float* b_ih1 = (const float*)d_in[7];
  const float* b_hh1 = (const float*)d_in[8];
  const float* fc1_w = (const float*)d_in[9];
  const float* fc1_b = (const float*)d_in[10];
  const float* fc2_w = (const float*)d_in[11];
  const float* fc2_b = (const float*)d_in[12];
  float* out = (float*)d_out;

  lstm_mfma5<<<NBLK, NTH, 0, stream>>>(
      x, w_ih0, w_hh0, b_ih0, b_hh0, w_ih1, w_hh1, b_ih1, b_hh1,
      fc1_w, fc1_b, fc2_w, fc2_b, out);
}

// Round 10
// 475.439 us; speedup vs baseline: 1.0104x; 1.0104x over previous
//
#include <hip/hip_runtime.h>
#include <stdint.h>

#define T_LEN 512
#define IN0   9
#define H     56
#define BG    8
#define NW    14
#define NTH   (NW * 64)        // 896 threads, 14 waves; wave w owns n' in [16w,16w+16)
#define NBLK  256

typedef __attribute__((ext_vector_type(8))) short bfrag;   // 8 bf16
typedef __attribute__((ext_vector_type(4))) float ffrag;   // 4 fp32

#define MFMA(a,b,c) __builtin_amdgcn_mfma_f32_16x16x32_bf16((a),(b),(c),0,0,0)

__device__ __forceinline__ uint32_t bf16hi(float x) {
  uint32_t u = __float_as_uint(x);
  return (u + 0x7FFFu + ((u >> 16) & 1u)) & 0xFFFF0000u;
}
// RNE both halves (weights, init-time only)
__device__ __forceinline__ void split_bf16(float x, short& hs, short& ls) {
  uint32_t hb = bf16hi(x);
  float lf = x - __uint_as_float(hb);
  hs = (short)(hb >> 16);
  ls = (short)(bf16hi(lf) >> 16);
}
// RNE hi, truncated lo (loop-time: error <= 2^-17 relative)
__device__ __forceinline__ void split_bf16t(float x, short& hs, short& ls) {
  uint32_t hb = bf16hi(x);
  float lf = x - __uint_as_float(hb);
  hs = (short)(hb >> 16);
  ls = (short)(__float_as_uint(lf) >> 16);
}
// v = v + lane(v ^ 8), via DPP row_ror:8 (xor-8 == ror-8 within 16-lane rows)
__device__ __forceinline__ float dpp8_add(float v) {
  int p = __builtin_amdgcn_update_dpp(0, __float_as_int(v), 0x128, 0xF, 0xF, true);
  return v + __int_as_float(p);
}
__device__ __forceinline__ float rcp_f(float v)  { return __builtin_amdgcn_rcpf(v); }
__device__ __forceinline__ float sigm_f(float v) { return rcp_f(1.0f + __expf(-v)); }
__device__ __forceinline__ float tanh_f(float v) { return 1.0f - 2.0f * rcp_f(1.0f + __expf(2.0f * v)); }

__global__ __launch_bounds__(NTH, 4)
void lstm_mfma6(const float* __restrict__ x,
                const float* __restrict__ w_ih0, const float* __restrict__ w_hh0,
                const float* __restrict__ b_ih0, const float* __restrict__ b_hh0,
                const float* __restrict__ w_ih1, const float* __restrict__ w_hh1,
                const float* __restrict__ b_ih1, const float* __restrict__ b_hh1,
                const float* __restrict__ fc1_w, const float* __restrict__ fc1_b,
                const float* __restrict__ fc2_w, const float* __restrict__ fc2_b,
                float* __restrict__ out)
{
  // h-state as MFMA B-operand: B[k = h-element j (L0: k56..63 = x)][n = batch-slot]
  // cols 0..7 = hi(h for batch n), cols 8..15 = lo residual. Fragment-linear.
  __shared__ __align__(16) short sB[4][1024];
  __shared__ float sF[BG * H];
  __shared__ float sY[BG * 28];

  const int tid  = threadIdx.x;
  const int lane = tid & 63;
  const int w    = tid >> 6;
  const int c16  = lane & 15;
  const int quad = lane >> 4;

  const int np   = 16 * w + c16;       // n' = 4j+g (A-operand M index)
  const int jb   = np >> 2, gb = np & 3;
  const int wrow = gb * H + jb;

  for (int i = tid; i < (int)(sizeof(sB) / 4); i += NTH) ((int*)sB)[i] = 0;

  // ---- A-fragments (weights, bf16 hi/lo): A[m=c16][k=quad*8+jj] ----
  bfrag B0h[2], B0l[2], Buh[2], Bul[2], Bhh[2], Bhl[2];
  #pragma unroll
  for (int s = 0; s < 2; ++s) {
    union { short sh[8]; bfrag v; } a0h, a0l, auh, aul, ahh, ahl;
    #pragma unroll
    for (int jj = 0; jj < 8; ++jj) {
      const int k = 32 * s + quad * 8 + jj;
      const float w0 = (k < H) ? w_hh0[wrow * H + k] : w_ih0[wrow * IN0 + (k - 56)];
      const float wu = (k < H) ? w_ih1[wrow * H + k] : 0.0f;
      const float wh = (k < H) ? w_hh1[wrow * H + k] : 0.0f;
      split_bf16(w0, a0h.sh[jj], a0l.sh[jj]);
      split_bf16(wu, auh.sh[jj], aul.sh[jj]);
      split_bf16(wh, ahh.sh[jj], ahl.sh[jj]);
    }
    B0h[s] = a0h.v; B0l[s] = a0l.v;
    Buh[s] = auh.v; Bul[s] = aul.v;
    Bhh[s] = ahh.v; Bhl[s] = ahl.v;
  }

  // D rows m = 4*quad + r -> gate g=r of j4 = 4w+quad. Bias rides C on hi cols only.
  const int j4 = 4 * w + quad;
  ffrag bias0f, bias1f;
  #pragma unroll
  for (int r = 0; r < 4; ++r) {
    const float v0 = b_ih0[r * H + j4] + b_hh0[r * H + j4];
    const float v1 = b_ih1[r * H + j4] + b_hh1[r * H + j4];
    bias0f[r] = (c16 < 8) ? v0 : 0.0f;
    bias1f[r] = (c16 < 8) ? v1 : 0.0f;
  }
  const ffrag zerof = { 0.f, 0.f, 0.f, 0.f };

  // act identity: lay=0 (c16<8) -> act1 element (b, j4); lay=1 -> act0 (b, j4)
  const int lay = (lane >> 3) & 1;
  const int b   = lane & 7;
  float wx8a[4];
  #pragma unroll
  for (int r = 0; r < 4; ++r)
    wx8a[r] = lay ? w_ih0[(r * H + j4) * IN0 + 8] : 0.0f;

  // h store offsets
  const int kk   = j4 & 31;
  const int offE = (j4 >> 5) * 512 + ((kk >> 3) * 16 + b) * 8 + (kk & 7);
  short* const hp0 = &sB[0][0] + (lay ? 0 : 3 * 1024) + offE;       // RR=0 regions
  short* const hp1 = &sB[0][0] + (lay ? 1 * 1024 : 2 * 1024) + offE; // RR=1 + prologue

  // x staging identity (wave 0, upper half-lanes)
  const int shalf = lane >> 5;
  const int sbq   = (lane >> 2) & 7;
  const int sjlc  = lane & 3;
  const int offX  = 512 + (48 + sbq) * 8 + 2 * sjlc;
  short* const xst0 = &sB[0][0] + offX;
  short* const xst1 = &sB[1][0] + offX;
  const short* const sBr = &sB[0][0];

  const float* xp8 = x + (size_t)(blockIdx.x * BG + b)   * T_LEN * IN0 + 8;
  const float* xps = x + (size_t)(blockIdx.x * BG + sbq) * T_LEN * IN0 + IN0 + 2 * sjlc;

  float cst = 0.f;                     // lay0: c1, lay1: c0
  __syncthreads();                     // sB zeros visible

  // ---- stage x(0) into sB[0] ----
  if (w == 0 && shalf) {
    const float xa = xps[-IN0], xb = xps[1 - IN0];
    short ah, al2, bh, bl2;
    split_bf16t(xa, ah, al2); split_bf16t(xb, bh, bl2);
    *(uint32_t*)xst0        = (uint16_t)ah  | ((uint32_t)(uint16_t)bh  << 16);
    *(uint32_t*)(xst0 + 64) = (uint16_t)al2 | ((uint32_t)(uint16_t)bl2 << 16);
  }
  __syncthreads();

  // ---- prologue: L0(0) gates + act0(0) -> h0(0) into sB[1]; stage x(1) ----
  {
    bfrag U0 = *(const bfrag*)(sBr + lane * 8);
    bfrag U1 = *(const bfrag*)(sBr + 512 + lane * 8);
    ffrag a0 = MFMA(B0h[0], U0, bias0f);
    a0 = MFMA(B0h[1], U1, a0);
    a0 = MFMA(B0l[0], U0, a0);
    a0 = MFMA(B0l[1], U1, a0);
    const float x8v = xp8[0];
    xp8 += IN0;
    float s0[4];
    #pragma unroll
    for (int r = 0; r < 4; ++r) s0[r] = dpp8_add(a0[r]);
    if (lay) {
      const float gi = fmaf(wx8a[0], x8v, s0[0]);
      const float gf = fmaf(wx8a[1], x8v, s0[1]);
      const float gg = fmaf(wx8a[2], x8v, s0[2]);
      const float go = fmaf(wx8a[3], x8v, s0[3]);
      const float iv = sigm_f(gi), fv = sigm_f(gf), gv = tanh_f(gg), ov = sigm_f(go);
      cst = fmaf(fv, cst, iv * gv);
      const float hv = ov * tanh_f(cst);
      short hs, hl; split_bf16t(hv, hs, hl);
      hp1[0] = hs; hp1[64] = hl;
    }
    if (w == 0 && shalf) {
      const float xa = xps[0], xb = xps[1];
      short ah, al2, bh, bl2;
      split_bf16t(xa, ah, al2); split_bf16t(xb, bh, bl2);
      *(uint32_t*)xst1        = (uint16_t)ah  | ((uint32_t)(uint16_t)bh  << 16);
      *(uint32_t*)(xst1 + 64) = (uint16_t)al2 | ((uint32_t)(uint16_t)bl2 << 16);
      xps += IN0;
    }
    __syncthreads();
  }

#define REGION(RR, L0PART, XSTG, LASTR)                                         \
  {                                                                             \
    bfrag U0 = *(const bfrag*)(sBr + (RR ^ 1) * 1024 + lane * 8);               \
    bfrag U1 = *(const bfrag*)(sBr + (RR ^ 1) * 1024 + 512 + lane * 8);         \
    bfrag H0 = *(const bfrag*)(sBr + (2 + RR) * 1024 + lane * 8);               \
    bfrag H1 = *(const bfrag*)(sBr + (2 + RR) * 1024 + 512 + lane * 8);         \
    float x8v = 0.0f;                                                           \
    if (L0PART) { x8v = xp8[0]; xp8 += IN0; }                                   \
    /* three independent MFMA chains (depth 4) */                               \
    ffrag aH = MFMA(Bhh[0], H0, bias1f);                                        \
    aH = MFMA(Bhh[1], H1, aH);                                                  \
    aH = MFMA(Bhl[0], H0, aH);                                                  \
    aH = MFMA(Bhl[1], H1, aH);                                                  \
    ffrag aU = MFMA(Buh[0], U0, zerof);                                         \
    aU = MFMA(Buh[1], U1, aU);                                                  \
    aU = MFMA(Bul[0], U0, aU);                                                  \
    aU = MFMA(Bul[1], U1, aU);                                                  \
    ffrag a0;                                                                   \
    if (L0PART) {                                                               \
      a0 = MFMA(B0h[0], U0, bias0f);                                            \
      a0 = MFMA(B0h[1], U1, a0);                                                \
      a0 = MFMA(B0l[0], U0, a0);                                                \
      a0 = MFMA(B0l[1], U1, a0);                                                \
    }                                                                           \
    if (!LASTR) {                                                               \
      float sv[4];                                                              \
      _Pragma("unroll")                                                         \
      for (int r = 0; r < 4; ++r) {                                             \
        const float s1 = dpp8_add(aH[r] + aU[r]);                               \
        const float s0 = dpp8_add(a0[r]);                                       \
        sv[r] = lay ? s0 : s1;                                                  \
      }                                                                         \
      const float gi = fmaf(wx8a[0], x8v, sv[0]);                               \
      const float gf = fmaf(wx8a[1], x8v, sv[1]);                               \
      const float gg = fmaf(wx8a[2], x8v, sv[2]);                               \
      const float go = fmaf(wx8a[3], x8v, sv[3]);                               \
      const float iv = sigm_f(gi), fv = sigm_f(gf);                             \
      const float gv = tanh_f(gg), ov = sigm_f(go);                             \
      cst = fmaf(fv, cst, iv * gv);                                             \
      const float hv = ov * tanh_f(cst);                                        \
      short hs, hl; split_bf16t(hv, hs, hl);                                    \
      short* hb = (RR == 0) ? hp0 : hp1;                                        \
      hb[0] = hs; hb[64] = hl;                                                  \
    } else {                                                                    \
      float s1[4];                                                              \
      _Pragma("unroll")                                                         \
      for (int r = 0; r < 4; ++r) s1[r] = dpp8_add(aH[r] + aU[r]);              \
      if (lay == 0) {                                                           \
        const float iv = sigm_f(s1[0]), fv = sigm_f(s1[1]);                     \
        const float gv = tanh_f(s1[2]), ov = sigm_f(s1[3]);                     \
        cst = fmaf(fv, cst, iv * gv);                                           \
        sF[b * H + j4] = ov * tanh_f(cst);                                      \
      }                                                                         \
    }                                                                           \
    if (XSTG) {                                                                 \
      if (w == 0 && shalf) {                                                    \
        const float xa = xps[0], xb = xps[1];                                   \
        short ah, al2, bh, bl2;                                                 \
        split_bf16t(xa, ah, al2); split_bf16t(xb, bh, bl2);                     \
        short* xb_ = (RR == 0) ? xst0 : xst1;                                   \
        *(uint32_t*)xb_        = (uint16_t)ah  | ((uint32_t)(uint16_t)bh  << 16); \
        *(uint32_t*)(xb_ + 64) = (uint16_t)al2 | ((uint32_t)(uint16_t)bl2 << 16); \
        xps += IN0;                                                             \
      }                                                                         \
    }                                                                           \
    __syncthreads();                                                            \
  }

  // t = 0..509 (255 pairs), then 510 (no staging), then 511 (L1-only)
  for (int it = 0; it < 255; ++it) {
    REGION(0, 1, 1, 0)
    REGION(1, 1, 1, 0)
  }
  REGION(0, 1, 0, 0)
  REGION(1, 0, 0, 1)
#undef REGION

  // ---- FC head on final h1 ----
  if (tid < 28 * BG) {
    const int m  = tid >> 3;
    const int bb = tid & 7;
    float acc = fc1_b[m];
    const float4* w4 = (const float4*)(fc1_w + m * H);
    const float4* h4 = (const float4*)(sF + bb * H);
    #pragma unroll
    for (int qq = 0; qq < H / 4; ++qq) {
      const float4 wv4 = w4[qq], hv4 = h4[qq];
      acc = fmaf(wv4.x, hv4.x, acc);
      acc = fmaf(wv4.y, hv4.y, acc);
      acc = fmaf(wv4.z, hv4.z, acc);
      acc = fmaf(wv4.w, hv4.w, acc);
    }
    sY[bb * 28 + m] = fmaxf(acc, 0.0f);
  }
  __syncthreads();
  if (tid < BG) {
    float acc = fc2_b[0];
    #pragma unroll
    for (int m = 0; m < 28; ++m)
      acc = fmaf(fc2_w[m], sY[tid * 28 + m], acc);
    out[blockIdx.x * BG + tid] = acc;
  }
}

extern "C" void kernel_launch(void* const* d_in, const int* in_sizes, int n_in,
                              void* d_out, int out_size, void* d_ws, size_t ws_size,
                              hipStream_t stream)
{
  const float* x     = (const float*)d_in[0];
  const float* w_ih0 = (const float*)d_in[1];
  const float* w_hh0 = (const float*)d_in[2];
  const float* b_ih0 = (const float*)d_in[3];
  const float* b_hh0 = (const float*)d_in[4];
  const float* w_ih1 = (const float*)d_in[5];
  const float* w_hh1 = (const float*)d_in[6];
  const float* b_ih1 = (const float*)d_in[7];
  const float* b_hh1 = (const float*)d_in[8];
  const float* fc1_w = (const float*)d_in[9];
  const float* fc1_b = (const float*)d_in[10];
  const float* fc2_w = (const float*)d_in[11];
  const float* fc2_b = (const float*)d_in[12];
  float* out = (float*)d_out;

  lstm_mfma6<<<NBLK, NTH, 0, stream>>>(
      x, w_ih0, w_hh0, b_ih0, b_hh0, w_ih1, w_hh1, b_ih1, b_hh1,
      fc1_w, fc1_b, fc2_w, fc2_b, out);
}

// Round 11
// 429.165 us; speedup vs baseline: 1.1193x; 1.1078x over previous
//
#include <hip/hip_runtime.h>
#include <stdint.h>

#define T_LEN 512
#define IN0   9
#define H     56
#define BG    8
#define NW    14
#define NTH   (NW * 64)        // 896 threads, 14 waves; wave w owns n' in [16w,16w+16)
#define NBLK  256

typedef __attribute__((ext_vector_type(8))) short bfrag;   // 8 bf16
typedef __attribute__((ext_vector_type(4))) float ffrag;   // 4 fp32

#define MFMA(a,b,c) __builtin_amdgcn_mfma_f32_16x16x32_bf16((a),(b),(c),0,0,0)

__device__ __forceinline__ uint32_t bf16hi(float x) {
  uint32_t u = __float_as_uint(x);
  return (u + 0x7FFFu + ((u >> 16) & 1u)) & 0xFFFF0000u;
}
// RNE both halves (weights, init-time only)
__device__ __forceinline__ void split_bf16(float x, short& hs, short& ls) {
  uint32_t hb = bf16hi(x);
  float lf = x - __uint_as_float(hb);
  hs = (short)(hb >> 16);
  ls = (short)(bf16hi(lf) >> 16);
}
// RNE hi, truncated lo (loop-time)
__device__ __forceinline__ void split_bf16t(float x, short& hs, short& ls) {
  uint32_t hb = bf16hi(x);
  float lf = x - __uint_as_float(hb);
  hs = (short)(hb >> 16);
  ls = (short)(__float_as_uint(lf) >> 16);
}
// v = v + lane(v ^ 8), via DPP row_ror:8 (xor-8 == ror-8 within 16-lane rows)
__device__ __forceinline__ float dpp8_add(float v) {
  int p = __builtin_amdgcn_update_dpp(0, __float_as_int(v), 0x128, 0xF, 0xF, true);
  return v + __int_as_float(p);
}
__device__ __forceinline__ float rcp_f(float v)  { return __builtin_amdgcn_rcpf(v); }
__device__ __forceinline__ float sigm_f(float v) { return rcp_f(1.0f + __expf(-v)); }
__device__ __forceinline__ float tanh_f(float v) { return 1.0f - 2.0f * rcp_f(1.0f + __expf(2.0f * v)); }

__global__ __launch_bounds__(NTH, 4)
void lstm_mfma7(const float* __restrict__ x,
                const float* __restrict__ w_ih0, const float* __restrict__ w_hh0,
                const float* __restrict__ b_ih0, const float* __restrict__ b_hh0,
                const float* __restrict__ w_ih1, const float* __restrict__ w_hh1,
                const float* __restrict__ b_ih1, const float* __restrict__ b_hh1,
                const float* __restrict__ fc1_w, const float* __restrict__ fc1_b,
                const float* __restrict__ fc2_w, const float* __restrict__ fc2_b,
                float* __restrict__ out)
{
  // h-state as MFMA B-operand: B[k = h-element j (L0: k56..63 = x)][n = batch-slot]
  // cols 0..7 = hi(h for batch n), cols 8..15 = lo residual. Fragment-linear.
  // Precision scheme: h/x always hi+lo (cols); weights: L0 = hi+lo passes,
  // L1 (U and H ops) = hi pass only (error ~8e-4 pre-act << 1.6e-3 threshold).
  __shared__ __align__(16) short sB[4][1024];
  __shared__ float sF[BG * H];
  __shared__ float sY[BG * 28];

  const int tid  = threadIdx.x;
  const int lane = tid & 63;
  const int w    = tid >> 6;
  const int c16  = lane & 15;
  const int quad = lane >> 4;

  const int np   = 16 * w + c16;       // n' = 4j+g (A-operand M index)
  const int jb   = np >> 2, gb = np & 3;
  const int wrow = gb * H + jb;

  for (int i = tid; i < (int)(sizeof(sB) / 4); i += NTH) ((int*)sB)[i] = 0;

  // ---- A-fragments (weights): A[m=c16][k=quad*8+jj] ----
  bfrag B0h[2], B0l[2], Buh[2], Bhh[2];
  #pragma unroll
  for (int s = 0; s < 2; ++s) {
    union { short sh[8]; bfrag v; } a0h, a0l, auh, ahh;
    #pragma unroll
    for (int jj = 0; jj < 8; ++jj) {
      const int k = 32 * s + quad * 8 + jj;
      const float w0 = (k < H) ? w_hh0[wrow * H + k] : w_ih0[wrow * IN0 + (k - 56)];
      const float wu = (k < H) ? w_ih1[wrow * H + k] : 0.0f;
      const float wh = (k < H) ? w_hh1[wrow * H + k] : 0.0f;
      split_bf16(w0, a0h.sh[jj], a0l.sh[jj]);
      short dum;
      split_bf16(wu, auh.sh[jj], dum);   // RNE hi only
      split_bf16(wh, ahh.sh[jj], dum);
    }
    B0h[s] = a0h.v; B0l[s] = a0l.v;
    Buh[s] = auh.v; Bhh[s] = ahh.v;
  }

  // D rows m = 4*quad + r -> gate g=r of j4 = 4w+quad. Bias rides C on hi cols only.
  const int j4 = 4 * w + quad;
  ffrag bias0f, bias1f;
  #pragma unroll
  for (int r = 0; r < 4; ++r) {
    const float v0 = b_ih0[r * H + j4] + b_hh0[r * H + j4];
    const float v1 = b_ih1[r * H + j4] + b_hh1[r * H + j4];
    bias0f[r] = (c16 < 8) ? v0 : 0.0f;
    bias1f[r] = (c16 < 8) ? v1 : 0.0f;
  }
  const ffrag zerof = { 0.f, 0.f, 0.f, 0.f };

  // act identity: lay=0 (c16<8) -> act1 element (b, j4); lay=1 -> act0 (b, j4)
  const int lay = (lane >> 3) & 1;
  const int b   = lane & 7;
  float wx8a[4];
  #pragma unroll
  for (int r = 0; r < 4; ++r)
    wx8a[r] = lay ? w_ih0[(r * H + j4) * IN0 + 8] : 0.0f;

  // h store offsets
  const int kk   = j4 & 31;
  const int offE = (j4 >> 5) * 512 + ((kk >> 3) * 16 + b) * 8 + (kk & 7);
  short* const hp0 = &sB[0][0] + (lay ? 0 : 3 * 1024) + offE;        // RR=0 regions
  short* const hp1 = &sB[0][0] + (lay ? 1 * 1024 : 2 * 1024) + offE; // RR=1 + prologue

  // x staging: wave 0 handles even timesteps -> sB[0]; wave 1 odd -> sB[1]
  const int shalf = lane >> 5;
  const int sbq   = (lane >> 2) & 7;
  const int sjlc  = lane & 3;
  const int offX  = 512 + (48 + sbq) * 8 + 2 * sjlc;
  short* const xst0 = &sB[0][0] + offX;
  short* const xst1 = &sB[1][0] + offX;
  const short* const sBr = &sB[0][0];

  const float* xp8 = x + (size_t)(blockIdx.x * BG + b) * T_LEN * IN0 + 8;
  // wave0: stages x(0),x(2),...; wave1: x(1),x(3),...
  const float* xps = x + (size_t)(blockIdx.x * BG + sbq) * T_LEN * IN0
                   + (size_t)w * IN0 + 2 * sjlc;

  float cst = 0.f;                     // lay0: c1, lay1: c0
  __syncthreads();                     // sB zeros visible

  // ---- stage x(0) into sB[0] (wave 0) ----
  if (w == 0 && shalf) {
    const float xa = xps[0], xb = xps[1];
    short ah, al2, bh, bl2;
    split_bf16t(xa, ah, al2); split_bf16t(xb, bh, bl2);
    *(uint32_t*)xst0        = (uint16_t)ah  | ((uint32_t)(uint16_t)bh  << 16);
    *(uint32_t*)(xst0 + 64) = (uint16_t)al2 | ((uint32_t)(uint16_t)bl2 << 16);
    xps += 2 * IN0;                    // -> x(2)
  }
  __syncthreads();

  // ---- prologue: L0(0) gates + act0(0) -> h0(0) into sB[1]; wave1 stages x(1) ----
  {
    bfrag U0 = *(const bfrag*)(sBr + lane * 8);
    bfrag U1 = *(const bfrag*)(sBr + 512 + lane * 8);
    ffrag a0 = MFMA(B0h[0], U0, bias0f);
    a0 = MFMA(B0h[1], U1, a0);
    a0 = MFMA(B0l[0], U0, a0);
    a0 = MFMA(B0l[1], U1, a0);
    const float x8v = xp8[0];
    xp8 += IN0;
    float s0[4];
    #pragma unroll
    for (int r = 0; r < 4; ++r) s0[r] = dpp8_add(a0[r]);
    if (lay) {
      const float gi = fmaf(wx8a[0], x8v, s0[0]);
      const float gf = fmaf(wx8a[1], x8v, s0[1]);
      const float gg = fmaf(wx8a[2], x8v, s0[2]);
      const float go = fmaf(wx8a[3], x8v, s0[3]);
      const float iv = sigm_f(gi), fv = sigm_f(gf), gv = tanh_f(gg), ov = sigm_f(go);
      cst = fmaf(fv, cst, iv * gv);
      const float hv = ov * tanh_f(cst);
      short hs, hl; split_bf16t(hv, hs, hl);
      hp1[0] = hs; hp1[64] = hl;
    }
    if (w == 1 && shalf) {             // stage x(1) into sB[1]
      const float xa = xps[0], xb = xps[1];
      short ah, al2, bh, bl2;
      split_bf16t(xa, ah, al2); split_bf16t(xb, bh, bl2);
      *(uint32_t*)xst1        = (uint16_t)ah  | ((uint32_t)(uint16_t)bh  << 16);
      *(uint32_t*)(xst1 + 64) = (uint16_t)al2 | ((uint32_t)(uint16_t)bl2 << 16);
      xps += 2 * IN0;                  // -> x(3)
    }
    __syncthreads();
  }

#define REGION(RR, L0PART, XSTG, LASTR)                                         \
  {                                                                             \
    bfrag U0 = *(const bfrag*)(sBr + (RR ^ 1) * 1024 + lane * 8);               \
    bfrag U1 = *(const bfrag*)(sBr + (RR ^ 1) * 1024 + 512 + lane * 8);         \
    bfrag H0 = *(const bfrag*)(sBr + (2 + RR) * 1024 + lane * 8);               \
    bfrag H1 = *(const bfrag*)(sBr + (2 + RR) * 1024 + 512 + lane * 8);         \
    float x8v = 0.0f;                                                           \
    if (L0PART) { x8v = xp8[0]; xp8 += IN0; }                                   \
    /* L0 chain first (consumer is far away) */                                 \
    ffrag a0;                                                                   \
    if (L0PART) {                                                               \
      a0 = MFMA(B0h[0], U0, bias0f);                                            \
      a0 = MFMA(B0h[1], U1, a0);                                                \
      a0 = MFMA(B0l[0], U0, a0);                                                \
      a0 = MFMA(B0l[1], U1, a0);                                                \
    }                                                                           \
    /* L1: hi-weight passes only */                                             \
    ffrag aH = MFMA(Bhh[0], H0, bias1f);                                        \
    aH = MFMA(Bhh[1], H1, aH);                                                  \
    ffrag aU = MFMA(Buh[0], U0, zerof);                                         \
    aU = MFMA(Buh[1], U1, aU);                                                  \
    if (!LASTR) {                                                               \
      float sv[4];                                                              \
      _Pragma("unroll")                                                         \
      for (int r = 0; r < 4; ++r) {                                             \
        const float s1 = dpp8_add(aH[r] + aU[r]);                               \
        const float s0 = dpp8_add(a0[r]);                                       \
        sv[r] = lay ? s0 : s1;                                                  \
      }                                                                         \
      const float gi = fmaf(wx8a[0], x8v, sv[0]);                               \
      const float gf = fmaf(wx8a[1], x8v, sv[1]);                               \
      const float gg = fmaf(wx8a[2], x8v, sv[2]);                               \
      const float go = fmaf(wx8a[3], x8v, sv[3]);                               \
      const float iv = sigm_f(gi), fv = sigm_f(gf);                             \
      const float gv = tanh_f(gg), ov = sigm_f(go);                             \
      cst = fmaf(fv, cst, iv * gv);                                             \
      const float hv = ov * tanh_f(cst);                                        \
      short hs, hl; split_bf16t(hv, hs, hl);                                    \
      short* hb = (RR == 0) ? hp0 : hp1;                                        \
      hb[0] = hs; hb[64] = hl;                                                  \
    } else {                                                                    \
      float s1[4];                                                              \
      _Pragma("unroll")                                                         \
      for (int r = 0; r < 4; ++r) s1[r] = dpp8_add(aH[r] + aU[r]);              \
      if (lay == 0) {                                                           \
        const float iv = sigm_f(s1[0]), fv = sigm_f(s1[1]);                     \
        const float gv = tanh_f(s1[2]), ov = sigm_f(s1[3]);                     \
        cst = fmaf(fv, cst, iv * gv);                                           \
        sF[b * H + j4] = ov * tanh_f(cst);                                      \
      }                                                                         \
    }                                                                           \
    if (XSTG) {                                                                 \
      /* RR==0 regions stage even timesteps (wave0); RR==1 odd (wave1) */       \
      if (w == RR && shalf) {                                                   \
        const float xa = xps[0], xb = xps[1];                                   \
        short ah, al2, bh, bl2;                                                 \
        split_bf16t(xa, ah, al2); split_bf16t(xb, bh, bl2);                     \
        short* xb_ = (RR == 0) ? xst0 : xst1;                                   \
        *(uint32_t*)xb_        = (uint16_t)ah  | ((uint32_t)(uint16_t)bh  << 16); \
        *(uint32_t*)(xb_ + 64) = (uint16_t)al2 | ((uint32_t)(uint16_t)bl2 << 16); \
        xps += 2 * IN0;                                                         \
      }                                                                         \
    }                                                                           \
    __syncthreads();                                                            \
  }

  // t = 0..509 (255 pairs), then 510 (no staging), then 511 (L1-only)
  for (int it = 0; it < 255; ++it) {
    REGION(0, 1, 1, 0)
    REGION(1, 1, 1, 0)
  }
  REGION(0, 1, 0, 0)
  REGION(1, 0, 0, 1)
#undef REGION

  // ---- FC head on final h1 ----
  if (tid < 28 * BG) {
    const int m  = tid >> 3;
    const int bb = tid & 7;
    float acc = fc1_b[m];
    const float4* w4 = (const float4*)(fc1_w + m * H);
    const float4* h4 = (const float4*)(sF + bb * H);
    #pragma unroll
    for (int qq = 0; qq < H / 4; ++qq) {
      const float4 wv4 = w4[qq], hv4 = h4[qq];
      acc = fmaf(wv4.x, hv4.x, acc);
      acc = fmaf(wv4.y, hv4.y, acc);
      acc = fmaf(wv4.z, hv4.z, acc);
      acc = fmaf(wv4.w, hv4.w, acc);
    }
    sY[bb * 28 + m] = fmaxf(acc, 0.0f);
  }
  __syncthreads();
  if (tid < BG) {
    float acc = fc2_b[0];
    #pragma unroll
    for (int m = 0; m < 28; ++m)
      acc = fmaf(fc2_w[m], sY[tid * 28 + m], acc);
    out[blockIdx.x * BG + tid] = acc;
  }
}

extern "C" void kernel_launch(void* const* d_in, const int* in_sizes, int n_in,
                              void* d_out, int out_size, void* d_ws, size_t ws_size,
                              hipStream_t stream)
{
  const float* x     = (const float*)d_in[0];
  const float* w_ih0 = (const float*)d_in[1];
  const float* w_hh0 = (const float*)d_in[2];
  const float* b_ih0 = (const float*)d_in[3];
  const float* b_hh0 = (const float*)d_in[4];
  const float* w_ih1 = (const float*)d_in[5];
  const float* w_hh1 = (const float*)d_in[6];
  const float* b_ih1 = (const float*)d_in[7];
  const float* b_hh1 = (const float*)d_in[8];
  const float* fc1_w = (const float*)d_in[9];
  const float* fc1_b = (const float*)d_in[10];
  const float* fc2_w = (const float*)d_in[11];
  const float* fc2_b = (const float*)d_in[12];
  float* out = (float*)d_out;

  lstm_mfma7<<<NBLK, NTH, 0, stream>>>(
      x, w_ih0, w_hh0, b_ih0, b_hh0, w_ih1, w_hh1, b_ih1, b_hh1,
      fc1_w, fc1_b, fc2_w, fc2_b, out);
}